// Round 5
// baseline (513.255 us; speedup 1.0000x reference)
//
#include <hip/hip_runtime.h>
#include <cstdint>
#include <cstddef>

#define NS 512
#define NT 384
#define CZ 128

typedef __bf16 bf16x8 __attribute__((ext_vector_type(8)));
typedef __bf16 bf16x4 __attribute__((ext_vector_type(4)));
typedef float floatx16 __attribute__((ext_vector_type(16)));

// Workspace layouts (bf16 element units):
//   A_t[rb(96)][kc(64)][r(128)][e(8)]   panel = 65536 elems; r = (i&3)*32+c
//   B_t[pb(64)][kc(64)][r(192)][e(8)]   panel = 98304 elems; r = (j%6)*32+d
//   WT [e(128)][k(1024)]  k = (c>>4)*512 + d*16 + (c&15)
// k index = s;  kc = s>>3, e = s&7.

// ---------------------------------------------------------------------------
// WT: coalesced writes, scattered reads (Wout 512 KB is L2/L3-resident).
// ---------------------------------------------------------------------------
__global__ __launch_bounds__(256) void prep_wout(const float* __restrict__ Wout,
                                                 __bf16* __restrict__ WT) {
  const int idx = blockIdx.x * 256 + threadIdx.x;  // 131072
  const int e = idx >> 10, kk = idx & 1023;
  const int c = ((kk >> 9) << 4) | (kk & 15);
  const int d = (kk >> 4) & 31;
  WT[idx] = (__bf16)Wout[(size_t)(c * 32 + d) * CZ + e];
}

// ---------------------------------------------------------------------------
// rnorm[i][j] = 1/(sum_s m[s,i]m[s,j]+1e-3). 24 blocks x 384 thr; each block
// stages 16 i-columns (32 KB LDS) and streams mask rows coalesced over j.
// Total mask traffic 24 x 786 KB = 19 MB (was 302 MB).
// ---------------------------------------------------------------------------
__global__ __launch_bounds__(384) void prep_norm(const float* __restrict__ mask,
                                                 float* __restrict__ rnorm) {
  __shared__ float mi[16][512];
  const int i0 = blockIdx.x * 16, t = threadIdx.x;
  for (int idx = t; idx < 16 * 512; idx += 384) {
    const int ii = idx >> 9, s = idx & 511;
    mi[ii][s] = mask[(size_t)s * NT + i0 + ii];
  }
  __syncthreads();
  const int j = t;  // 0..383
  float acc[16];
#pragma unroll
  for (int ii = 0; ii < 16; ++ii) acc[ii] = 0.f;
  for (int s4 = 0; s4 < NS; s4 += 4) {
    float mj[4];
#pragma unroll
    for (int q = 0; q < 4; ++q) mj[q] = mask[(size_t)(s4 + q) * NT + j];
#pragma unroll
    for (int ii = 0; ii < 16; ++ii) {
      const float4 m4 = *(const float4*)&mi[ii][s4];  // wave-broadcast
      acc[ii] = fmaf(m4.x, mj[0], acc[ii]);
      acc[ii] = fmaf(m4.y, mj[1], acc[ii]);
      acc[ii] = fmaf(m4.z, mj[2], acc[ii]);
      acc[ii] = fmaf(m4.w, mj[3], acc[ii]);
    }
  }
#pragma unroll
  for (int ii = 0; ii < 16; ++ii)
    rnorm[(size_t)(i0 + ii) * NT + j] = 1.0f / (acc[ii] + 0.001f);
}

// ---------------------------------------------------------------------------
// LN + projections, writing the tiled layouts. One wave per (i, 64-s chunk).
// ---------------------------------------------------------------------------
__global__ __launch_bounds__(64) void ln_proj(const float* __restrict__ feat,
                                              const float* __restrict__ mask,
                                              const float* __restrict__ gamma,
                                              const float* __restrict__ beta,
                                              const float* __restrict__ Wa,
                                              const float* __restrict__ Wb,
                                              __bf16* __restrict__ Abf,
                                              __bf16* __restrict__ Bbf) {
  __shared__ float tile[64][65];
  __shared__ __bf16 T[32 * 72];
  const int bid = blockIdx.x;    // 3072
  const int i = bid >> 3;
  const int s0 = (bid & 7) << 6;
  const int lane = threadIdx.x;
  const int l31 = lane & 31, lh = lane >> 5;

  const int rsub = lane >> 4, cb = (lane & 15) * 4;
#pragma unroll
  for (int rr = 0; rr < 16; ++rr) {
    const int row = rr * 4 + rsub;
    const float4 v = *(const float4*)(feat + ((size_t)(s0 + row) * NT + i) * 64 + cb);
    tile[row][cb] = v.x; tile[row][cb + 1] = v.y;
    tile[row][cb + 2] = v.z; tile[row][cb + 3] = v.w;
  }
  __syncthreads();

  float x[64];
#pragma unroll
  for (int k = 0; k < 64; ++k) x[k] = tile[lane][k];  // lane = s-row

  float mu = 0.f;
#pragma unroll
  for (int k = 0; k < 64; ++k) mu += x[k];
  mu *= (1.0f / 64.0f);
  float var = 0.f;
#pragma unroll
  for (int k = 0; k < 64; ++k) { const float d = x[k] - mu; var += d * d; }
  var *= (1.0f / 64.0f);
  const float rstd = rsqrtf(var + 1e-5f);
#pragma unroll
  for (int k = 0; k < 64; ++k)
    x[k] = (x[k] - mu) * rstd * gamma[k] + beta[k];

  const float mv = mask[(size_t)(s0 + lane) * NT + i];

  // ---- projection A ----
  float acc[32];
#pragma unroll
  for (int c = 0; c < 32; ++c) acc[c] = 0.f;
#pragma unroll 8
  for (int k = 0; k < 64; ++k) {
    const float mk = x[k];
#pragma unroll
    for (int c = 0; c < 32; ++c) acc[c] = fmaf(mk, Wa[k * 32 + c], acc[c]);
  }
#pragma unroll
  for (int c = 0; c < 32; ++c) T[c * 72 + lane] = (__bf16)(acc[c] * mv);
  __syncthreads();
  {
    __bf16* dst = Abf + (size_t)(i >> 2) * 65536 + (size_t)(s0 >> 3) * 1024 +
                  (size_t)((i & 3) * 32) * 8;
#pragma unroll
    for (int q = 0; q < 4; ++q) {
      const bf16x8 v = *(const bf16x8*)(T + l31 * 72 + (q * 2 + lh) * 8);
      *(bf16x8*)(dst + (size_t)(q * 2 + lh) * 1024 + l31 * 8) = v;
    }
  }
  __syncthreads();

  // ---- projection B ----
#pragma unroll
  for (int c = 0; c < 32; ++c) acc[c] = 0.f;
#pragma unroll 8
  for (int k = 0; k < 64; ++k) {
    const float mk = x[k];
#pragma unroll
    for (int c = 0; c < 32; ++c) acc[c] = fmaf(mk, Wb[k * 32 + c], acc[c]);
  }
#pragma unroll
  for (int c = 0; c < 32; ++c) T[c * 72 + lane] = (__bf16)(acc[c] * mv);
  __syncthreads();
  {
    const int pb = i / 6, jl = i % 6;
    __bf16* dst = Bbf + (size_t)pb * 98304 + (size_t)(s0 >> 3) * 1536 +
                  (size_t)(jl * 32) * 8;
#pragma unroll
    for (int q = 0; q < 4; ++q) {
      const bf16x8 v = *(const bf16x8*)(T + l31 * 72 + (q * 2 + lh) * 8);
      *(bf16x8*)(dst + (size_t)(q * 2 + lh) * 1536 + l31 * 8) = v;
    }
  }
}

// ---------------------------------------------------------------------------
// Fused GEMM. Block 128(m) x 192(n), 4 waves (2x2), wave 64x96 (2x3 frags of
// 32x32x16). Double-buffered identity-copy LDS staging, 1 barrier per kt.
// acc = 96 AGPR -> launch_bounds(256,3): 3 blocks/CU, 12 waves/CU.
// Epilogue: 2 rounds over c-halves; P (32x648 elems, rows>=24 unused) aliased
// over staging; GEMM2 vs WT + bias + norm.
// ---------------------------------------------------------------------------
__global__ __launch_bounds__(256, 3) void opm_gemm(const __bf16* __restrict__ A,
                                                   const __bf16* __restrict__ B,
                                                   const __bf16* __restrict__ WT,
                                                   const float* __restrict__ bout,
                                                   const float* __restrict__ rnorm,
                                                   float* __restrict__ out) {
  __shared__ __align__(16) __bf16 smem[20736];  // 41472 B
  // staging buffer b at b*10240: As[4 kc][128][8] then Bs[4 kc][192][8]
  // P alias: addr(p,d,c') = p*648 + d*20 + (c' split lh*4/qp*8)

  const int t = threadIdx.x, lane = t & 63, wid = t >> 6;
  const int wm = wid & 1, wn = wid >> 1;
  const int l31 = lane & 31, lh = lane >> 5;

  // 4x4 supertile swizzle (grid 6144 = 96 bm x 64 bn)
  const int sq = blockIdx.x >> 4, r4 = blockIdx.x & 15;
  const int bm = (sq % 24) * 4 + (r4 & 3);
  const int bn = (sq / 24) * 4 + (r4 >> 2);

  const __bf16* Apan = A + (size_t)bm * 65536;
  const __bf16* Bpan = B + (size_t)bn * 98304;

  floatx16 acc[2][3];
#pragma unroll
  for (int fm = 0; fm < 2; ++fm)
#pragma unroll
    for (int fn = 0; fn < 3; ++fn)
#pragma unroll
      for (int q = 0; q < 16; ++q) acc[fm][fn][q] = 0.f;

#define STAGE(kt, buf)                                                          \
  {                                                                             \
    __bf16* dst = smem + (buf) * 10240;                                         \
    _Pragma("unroll")                                                           \
    for (int g2 = 0; g2 < 2; ++g2) {                                            \
      const int g = wid * 2 + g2;                                               \
      __builtin_amdgcn_global_load_lds(                                         \
          (const __attribute__((address_space(1))) void*)(Apan + (kt) * 4096 +  \
                                                          g * 512 + lane * 8),  \
          (__attribute__((address_space(3))) void*)(dst + g * 512), 16, 0, 0);  \
    }                                                                           \
    _Pragma("unroll")                                                           \
    for (int g3 = 0; g3 < 3; ++g3) {                                            \
      const int g = wid * 3 + g3;                                               \
      __builtin_amdgcn_global_load_lds(                                         \
          (const __attribute__((address_space(1))) void*)(Bpan + (kt) * 6144 +  \
                                                          g * 512 + lane * 8),  \
          (__attribute__((address_space(3))) void*)(dst + 4096 + g * 512),      \
          16, 0, 0);                                                            \
    }                                                                           \
  }

  STAGE(0, 0);
  int buf = 0;
  for (int kt = 0; kt < 16; ++kt) {
    __syncthreads();                    // drains stage loads of current buf
    if (kt < 15) STAGE(kt + 1, buf ^ 1);
    const __bf16* As = smem + buf * 10240;
    const __bf16* Bs = As + 4096;
#pragma unroll
    for (int ks = 0; ks < 2; ++ks) {
      const int ck = ks * 2 + lh;
      bf16x8 af[2], bf[3];
#pragma unroll
      for (int fm = 0; fm < 2; ++fm)
        af[fm] = *(const bf16x8*)(As + ck * 1024 + (wm * 64 + fm * 32 + l31) * 8);
#pragma unroll
      for (int fn = 0; fn < 3; ++fn)
        bf[fn] = *(const bf16x8*)(Bs + ck * 1536 + (wn * 96 + fn * 32 + l31) * 8);
#pragma unroll
      for (int fm = 0; fm < 2; ++fm)
#pragma unroll
        for (int fn = 0; fn < 3; ++fn)
          acc[fm][fn] = __builtin_amdgcn_mfma_f32_32x32x16_bf16(af[fm], bf[fn],
                                                                acc[fm][fn], 0, 0, 0);
    }
    buf ^= 1;
  }
#undef STAGE

  // ---- epilogue: 2 rounds over c-halves ----
  floatx16 z;
#pragma unroll
  for (int q = 0; q < 16; ++q) z[q] = 0.f;
  const int e = wid * 32 + l31;

#pragma unroll
  for (int round = 0; round < 2; ++round) {
    __syncthreads();  // staging reads (r0) / prev GEMM2 reads (r1) complete
    // scatter regs r = round*8 + qp*4 + j  (c = 16*round + 8*qp + 4*lh + j)
#pragma unroll
    for (int fm = 0; fm < 2; ++fm)
#pragma unroll
      for (int fn = 0; fn < 3; ++fn) {
        const int p = (wm * 2 + fm) * 6 + wn * 3 + fn;  // 0..23
        __bf16* base = smem + p * 648 + l31 * 20 + lh * 4;
#pragma unroll
        for (int qp = 0; qp < 2; ++qp) {
          bf16x4 v;
#pragma unroll
          for (int j = 0; j < 4; ++j)
            v[j] = (__bf16)acc[fm][fn][round * 8 + qp * 4 + j];
          *(bf16x4*)(base + qp * 8) = v;
        }
      }
    __syncthreads();
    // GEMM2: z[p][e] += P[p][k] * WT[e][round*512+k], K=512 (rows 24..31 junk)
    const __bf16* wrow = WT + (size_t)e * 1024 + round * 512 + lh * 8;
    const __bf16* prow = smem + l31 * 648 + lh * 8;
#pragma unroll 8
    for (int ks = 0; ks < 32; ++ks) {
      const bf16x8 pa = *(const bf16x8*)(prow + ks * 20);
      const bf16x8 wb = *(const bf16x8*)(wrow + ks * 16);
      z = __builtin_amdgcn_mfma_f32_32x32x16_bf16(pa, wb, z, 0, 0, 0);
    }
  }

  // out[i][j][e] = (z + bout[e]) * rnorm[i][j]; valid C rows p<24 are regs 0..11
  const float be = bout[e];
#pragma unroll
  for (int r = 0; r < 12; ++r) {
    const int p = (r & 3) + 8 * (r >> 2) + 4 * lh;  // 0..23
    const int i = bm * 4 + p / 6, j = bn * 6 + p % 6;
    const float rn = rnorm[(size_t)i * NT + j];
    out[((size_t)i * NT + j) * CZ + e] = (z[r] + be) * rn;
  }
}

// ---------------------------------------------------------------------------
extern "C" void kernel_launch(void* const* d_in, const int* in_sizes, int n_in,
                              void* d_out, int out_size, void* d_ws, size_t ws_size,
                              hipStream_t stream) {
  const float* feat  = (const float*)d_in[0];
  const float* mask  = (const float*)d_in[1];
  const float* gamma = (const float*)d_in[2];
  const float* beta  = (const float*)d_in[3];
  const float* Wa    = (const float*)d_in[4];
  const float* Wb    = (const float*)d_in[5];
  const float* Wout  = (const float*)d_in[6];
  const float* bout  = (const float*)d_in[7];
  float* out = (float*)d_out;

  char* ws = (char*)d_ws;
  const size_t A_BYTES = (size_t)96 * 65536 * sizeof(__bf16);  // 12,582,912
  const size_t B_BYTES = (size_t)64 * 98304 * sizeof(__bf16);  // 12,582,912
  __bf16* Abf = (__bf16*)(ws);
  __bf16* Bbf = (__bf16*)(ws + A_BYTES);
  __bf16* WT  = (__bf16*)(ws + A_BYTES + B_BYTES);
  float* rnorm = (float*)(ws + A_BYTES + B_BYTES + (size_t)CZ * 1024 * sizeof(__bf16));

  prep_wout<<<512, 256, 0, stream>>>(Wout, WT);
  prep_norm<<<24, 384, 0, stream>>>(mask, rnorm);
  ln_proj<<<NT * (NS / 64), 64, 0, stream>>>(feat, mask, gamma, beta, Wa, Wb, Abf, Bbf);
  opm_gemm<<<96 * 64, 256, 0, stream>>>(Abf, Bbf, WT, bout, rnorm, out);
}